// Round 5
// baseline (354.208 us; speedup 1.0000x reference)
//
#include <hip/hip_runtime.h>

// DigitCaps dynamic routing, MI355X — round 5: barrier-free sweep decomposition.
// vs round 3 (255us baseline; round-4's 3 confounded changes all reverted):
// routed passes split into D-sweep (logits) + softmax kernel + S-sweep (apply),
// each sweep a straight-line MFMA stream with NO barriers / NO LDS.
//
// u_hat[b,j,i,p] = sum_q x[b,i,q] W[j,i,p,q];  b=64, i=2048, j=32, p=32, q=16
//   A-sweep:  s1 = (1/32) sum_i u_hat                    ; v1 = squash(s1)
//   D-sweep:  d[b,j,i] = sum_p v[b,j,p] * u_hat[b,j,i,p]   (v = v1, then v1+v2)
//   softmax:  c[b,j,i] = softmax_j d[b,j,i]
//   S-sweep:  s = sum_i c * u_hat                        ; squash -> v2 / out
// Pass C logits = d1+d2 = sum_p (v1+v2)*u_hat (linearity) -> one D-sweep.
//
// MFMA 16x16x32 bf16: A k0-15 = hi(x), k16-31 = lo residual; B k-halves
// replicate W  => A-side fp32-exact, only W rounded once (absmax ~4e-3).

namespace {

using bfrag = __attribute__((ext_vector_type(8))) short;   // 8 bf16 = 4 VGPR
using ffrag = __attribute__((ext_vector_type(4))) float;   // 4 fp32 acc

constexpr int I_DIM = 2048;
constexpr int B_DIM = 64;
constexpr int N_DIM = 1024;   // j*32+p
constexpr int TI    = 16;     // i's per block

__device__ __forceinline__ unsigned short f2bf(float f) {
    unsigned int u = __float_as_uint(f);
    return (unsigned short)((u + 0x7fffu + ((u >> 16) & 1u)) >> 16);
}

// DPP row_ror reductions within 16-lane rows — pure VALU, no LDS pipe.
template<int CTRL>
__device__ __forceinline__ float dppf(float x) {
    return __int_as_float(
        __builtin_amdgcn_update_dpp(0, __float_as_int(x), CTRL, 0xF, 0xF, true));
}
__device__ __forceinline__ float sum16(float x) {
    x += dppf<0x121>(x); x += dppf<0x122>(x);
    x += dppf<0x124>(x); x += dppf<0x128>(x);
    return x;
}
__device__ __forceinline__ float max16(float x) {
    x = fmaxf(x, dppf<0x121>(x)); x = fmaxf(x, dppf<0x122>(x));
    x = fmaxf(x, dppf<0x124>(x)); x = fmaxf(x, dppf<0x128>(x));
    return x;
}

// ---------------- conversion kernels (r2/r3-proven) ----------------

// Wt[i][n][16] bf16  <-  W[j][i][p][q] fp32   (n = j*32+p)
__global__ __launch_bounds__(256)
void conv_w(const float* __restrict__ W, unsigned short* __restrict__ Wt) {
    const int t = blockIdx.x * 256 + threadIdx.x;          // (i,n)
    const int i = t >> 10, n = t & 1023;
    const float* src = W + ((((n >> 5) * I_DIM + i) * 32 + (n & 31)) << 4);
    unsigned int o[8];
    #pragma unroll
    for (int k = 0; k < 8; ++k)
        o[k] = (unsigned int)f2bf(src[2 * k]) | ((unsigned int)f2bf(src[2 * k + 1]) << 16);
    uint4* dst = reinterpret_cast<uint4*>(Wt + (size_t)t * 16);
    dst[0] = make_uint4(o[0], o[1], o[2], o[3]);
    dst[1] = make_uint4(o[4], o[5], o[6], o[7]);
}

// xT2[i][b][0:16]=hi(x), [16:32]=lo residual  <-  x[b][i][q] fp32
__global__ __launch_bounds__(256)
void conv_x(const float* __restrict__ x, unsigned short* __restrict__ xT2) {
    const int t = blockIdx.x * 256 + threadIdx.x;          // (i,b)
    const int i = t >> 6, b = t & 63;
    const float* src = x + (((size_t)b * I_DIM + i) << 4);
    unsigned int o[16];
    #pragma unroll
    for (int k = 0; k < 8; ++k) {
        const float f0 = src[2 * k], f1 = src[2 * k + 1];
        const unsigned short h0 = f2bf(f0), h1 = f2bf(f1);
        const float l0 = f0 - __uint_as_float(((unsigned int)h0) << 16);
        const float l1 = f1 - __uint_as_float(((unsigned int)h1) << 16);
        o[k]     = (unsigned int)h0       | ((unsigned int)h1 << 16);
        o[8 + k] = (unsigned int)f2bf(l0) | ((unsigned int)f2bf(l1) << 16);
    }
    uint4* dst = reinterpret_cast<uint4*>(xT2 + (size_t)t * 32);
    #pragma unroll
    for (int k = 0; k < 4; ++k)
        dst[k] = make_uint4(o[4 * k], o[4 * k + 1], o[4 * k + 2], o[4 * k + 3]);
}

// ---------------- MFMA sweeps (barrier-free) ----------------
// Block: 1024 thr = 16 waves, one 16-b group, all 32 j (2 j per wave), TI i's.
// MODE 0 (A): s += u_hat (uniform c applied at store)
// MODE 1 (D): d[i][b][j] = sum_p v*u_hat   (DPP p-reduce, li<2 scatter store)
// MODE 2 (S): s += c[i][b][j] * u_hat      (float2 broadcast c loads)
#define LOAD_FRAGS(iv)                                                          \
    do {                                                                        \
        const size_t i_ = (size_t)(iv);                                         \
        af = *reinterpret_cast<const bfrag*>(pa + (i_ << 11));                  \
        _Pragma("unroll")                                                       \
        for (int t = 0; t < 4; ++t)                                             \
            bfr[t] = *reinterpret_cast<const bfrag*>(pb[t] + (i_ << 14));       \
    } while (0)

template<int MODE>
__global__ __launch_bounds__(1024)
void caps_sweep(const unsigned short* __restrict__ Wt,   // [I][N][16] bf16
                const unsigned short* __restrict__ xT2,  // [I][64][32] bf16
                const float* __restrict__ v_in,          // [64][32][32] (D)
                const float* __restrict__ c_in,          // [I][64][32]  (S)
                float* __restrict__ d_out,               // [I][64][32]  (D)
                float* __restrict__ s_out)               // [64][1024]   (A,S)
{
    const int tid = threadIdx.x;
    const int w   = tid >> 6;          // wave 0..15
    const int l   = tid & 63;
    const int g   = l >> 4;            // 16-lane group 0..3
    const int li  = l & 15;
    const int j0  = w << 1;            // 2 j per wave
    const int qb  = (g & 1) << 3;      // B k-replication: q base 0/8
    const int g8  = g << 3;            // A k offset (hi 0-15, lo 16-31)

    // XCD-chunked bijective swizzle (512 blocks): same-i_tile blocks adjacent.
    const int bid = (int)blockIdx.x;
    const int V   = (bid & 7) * 64 + (bid >> 3);
    const int it  = V >> 2;
    const int b0  = (V & 3) << 4;

    const unsigned short* pa = xT2 + (b0 + li) * 32 + g8;
    const unsigned short* pb[4];
    #pragma unroll
    for (int t = 0; t < 4; ++t)
        pb[t] = Wt + (size_t)((((j0 + (t >> 1)) << 5) + ((t & 1) << 4) + li) * 16 + qb);

    // v in registers (D only): vr[r][t] = v[b0+4g+r][j0+(t>>1)][(t&1)*16+li]
    float vr[4][4];
    if (MODE == 1) {
        #pragma unroll
        for (int r = 0; r < 4; ++r)
            #pragma unroll
            for (int t = 0; t < 4; ++t)
                vr[r][t] = v_in[((b0 + (g << 2) + r) * 32 + j0 + (t >> 1)) * 32
                                + ((t & 1) << 4) + li];
    }

    bfrag af;
    bfrag bfr[4];
    LOAD_FRAGS(it * TI);               // prologue

    ffrag s[4];
    #pragma unroll
    for (int t = 0; t < 4; ++t) s[t] = ffrag{0.f, 0.f, 0.f, 0.f};

    for (int ii = 0; ii < TI; ++ii) {
        const int i = it * TI + ii;

        // c loads for this i (S only) — 4 float2, broadcast within 16-lane group
        float2 cw[4];
        if (MODE == 2) {
            #pragma unroll
            for (int r = 0; r < 4; ++r)
                cw[r] = *reinterpret_cast<const float2*>(
                    c_in + ((size_t)i * B_DIM + b0 + (g << 2) + r) * 32 + j0);
        }

        if (MODE == 0) {
            #pragma unroll
            for (int t = 0; t < 4; ++t)
                s[t] = __builtin_amdgcn_mfma_f32_16x16x32_bf16(af, bfr[t], s[t], 0, 0, 0);
            LOAD_FRAGS(it * TI + ((ii + 1 < TI) ? ii + 1 : ii));
            asm volatile("" ::: "memory");
        } else {
            ffrag u[4];
            #pragma unroll
            for (int t = 0; t < 4; ++t) {
                ffrag z{0.f, 0.f, 0.f, 0.f};
                u[t] = __builtin_amdgcn_mfma_f32_16x16x32_bf16(af, bfr[t], z, 0, 0, 0);
            }
            LOAD_FRAGS(it * TI + ((ii + 1 < TI) ? ii + 1 : ii));
            asm volatile("" ::: "memory");

            if (MODE == 1) {
                // d[b,j] = sum_p v*u  (p = (t&1)*16+li across 16 lanes)
                #pragma unroll
                for (int r = 0; r < 4; ++r) {
                    float d0 = u[0][r] * vr[r][0] + u[1][r] * vr[r][1];
                    float d1 = u[2][r] * vr[r][2] + u[3][r] * vr[r][3];
                    d0 = sum16(d0);
                    d1 = sum16(d1);
                    const float dsel = (li & 1) ? d1 : d0;
                    if (li < 2)
                        d_out[((size_t)i * B_DIM + b0 + (g << 2) + r) * 32 + j0 + li] = dsel;
                }
            } else {
                #pragma unroll
                for (int r = 0; r < 4; ++r) {
                    s[0][r] += cw[r].x * u[0][r];
                    s[1][r] += cw[r].x * u[1][r];
                    s[2][r] += cw[r].y * u[2][r];
                    s[3][r] += cw[r].y * u[3][r];
                }
            }
        }
    }

    if (MODE != 1) {
        const float sc = (MODE == 0) ? (1.f / 32.f) : 1.f;
        #pragma unroll
        for (int t = 0; t < 4; ++t)
            #pragma unroll
            for (int r = 0; r < 4; ++r)
                atomicAdd(&s_out[(b0 + (g << 2) + r) * N_DIM
                                 + ((j0 + (t >> 1)) << 5) + ((t & 1) << 4) + li],
                          s[t][r] * sc);
    }
}

// c[row][j] = softmax_j d[row][j], row = (i,b), 32 j per row (one per lane-of-32)
__global__ __launch_bounds__(1024)
void softmax_c(const float* __restrict__ d, float* __restrict__ c) {
    const int tid = threadIdx.x;
    const size_t row = (size_t)blockIdx.x * 32 + (tid >> 5);
    const int jx = tid & 31;
    const float bn = d[row * 32 + jx];
    float m = max16(bn);
    m = fmaxf(m, __shfl_xor(m, 16));
    const float e = __expf(bn - m);
    float ssum = sum16(e);
    ssum += __shfl_xor(ssum, 16);
    c[row * 32 + jx] = e / ssum;
}

// dst[row] = (base ? base[row] : 0) + squash(s[row]),  row = (b,j)
__global__ __launch_bounds__(256)
void squash_add(const float* __restrict__ s, const float* __restrict__ base,
                float* __restrict__ dst) {
    const int t = blockIdx.x * 256 + threadIdx.x;
    if (t >= B_DIM * 32) return;
    const float* sp = s + t * 32;
    float n2 = 0.f;
    #pragma unroll
    for (int p = 0; p < 32; ++p) { const float xv = sp[p]; n2 += xv * xv; }
    const float scl = n2 / ((1.f + n2) * sqrtf(n2 + 1e-7f));
    float* op = dst + t * 32;
    #pragma unroll
    for (int p = 0; p < 32; ++p)
        op[p] = (base ? base[t * 32 + p] : 0.f) + scl * sp[p];
}

} // namespace

extern "C" void kernel_launch(void* const* d_in, const int* in_sizes, int n_in,
                              void* d_out, int out_size, void* d_ws, size_t ws_size,
                              hipStream_t stream) {
    const float* x = (const float*)d_in[0];   // [64, 2048, 16]
    const float* W = (const float*)d_in[1];   // [32, 2048, 32, 16]
    float* out = (float*)d_out;               // [64, 32, 32]

    const size_t needW = (size_t)I_DIM * N_DIM * 16 * 2;   // 64 MB bf16 Wt
    const size_t needX = (size_t)I_DIM * B_DIM * 32 * 2;   // 8 MB bf16 xT2
    const size_t needD = (size_t)I_DIM * B_DIM * 32 * 4;   // 16 MB d
    const size_t needS = (size_t)B_DIM * N_DIM * 4;        // 256 KB

    char* pp = (char*)d_ws;
    unsigned short* Wt  = (unsigned short*)pp; pp += needW;
    unsigned short* xT2 = (unsigned short*)pp; pp += needX;
    float* dbuf = (float*)pp; pp += needD;
    float* cbuf = (float*)pp; pp += needD;
    float* s    = (float*)pp; pp += needS;
    float* v1   = (float*)pp; pp += needS;
    float* vs   = (float*)pp;
    (void)ws_size;

    conv_x<<<(I_DIM * B_DIM) / 256, 256, 0, stream>>>(x, xT2);
    conv_w<<<(I_DIM * N_DIM) / 256, 256, 0, stream>>>(W, Wt);

    const dim3 rg(512), rb(1024);
    const dim3 sg(I_DIM * B_DIM / 32), sb(1024);

    // pass A: uniform c = 1/32
    hipMemsetAsync(s, 0, needS, stream);
    caps_sweep<0><<<rg, rb, 0, stream>>>(Wt, xT2, nullptr, nullptr, nullptr, s);
    squash_add<<<8, 256, 0, stream>>>(s, nullptr, v1);

    // pass B: d1 = sum_p v1*u_hat ; c2 = softmax(d1) ; s2
    caps_sweep<1><<<rg, rb, 0, stream>>>(Wt, xT2, v1, nullptr, dbuf, nullptr);
    softmax_c<<<sg, sb, 0, stream>>>(dbuf, cbuf);
    hipMemsetAsync(s, 0, needS, stream);
    caps_sweep<2><<<rg, rb, 0, stream>>>(Wt, xT2, nullptr, cbuf, nullptr, s);
    squash_add<<<8, 256, 0, stream>>>(s, v1, vs);          // vs = v1 + v2

    // pass C: logits = sum_p (v1+v2)*u_hat (linearity)
    caps_sweep<1><<<rg, rb, 0, stream>>>(Wt, xT2, vs, nullptr, dbuf, nullptr);
    softmax_c<<<sg, sb, 0, stream>>>(dbuf, cbuf);
    hipMemsetAsync(s, 0, needS, stream);
    caps_sweep<2><<<rg, rb, 0, stream>>>(Wt, xT2, nullptr, cbuf, nullptr, s);
    squash_add<<<8, 256, 0, stream>>>(s, nullptr, out);
}

// Round 6
// 286.492 us; speedup vs baseline: 1.2364x; 1.2364x over previous
//
#include <hip/hip_runtime.h>

// DigitCaps dynamic routing, MI355X — round 6: fused 3-pass + LDS-staged Wt
// via global_load_lds + counted-vmcnt double buffering (T3/T4 pattern).
//
// u_hat[b,j,i,p] = sum_q x[b,i,q] W[j,i,p,q];  b=64, i=2048, j=32, p=32, q=16
// Pass A: s1 = (1/32) sum_i u_hat ; v1 = squash(s1)
// Pass B: per i: d=sum_p v1*u_hat ; c=softmax_j d ; s2 += c*u_hat ; v2=squash
// Pass C: v = v1+v2 (logits linear in v) ; out = squash(s3)
//
// MFMA 16x16x32 bf16: A k0-15 = hi(x), k16-31 = lo residual; B k-halves
// replicate W => A-side fp32-exact, only W rounded once (absmax ~4e-3).
//
// Layouts (chosen so global_load_lds stays linear AND ds_read_b128 is
// stride-16B = conflict-free):
//   Wt [i][h][n][8]  bf16 : h = q-half (0: q0-7, 1: q8-15), n = j*32+p
//   xT2[i][g][b][8]  bf16 : g = k-group (0: hi q0-7, 1: hi q8-15, 2/3: lo)

namespace {

using bfrag = __attribute__((ext_vector_type(8))) short;   // 8 bf16 = 4 VGPR
using ffrag = __attribute__((ext_vector_type(4))) float;   // 4 fp32 acc

constexpr int I_DIM = 2048;
constexpr int B_DIM = 64;
constexpr int N_DIM = 1024;
constexpr int TI    = 16;     // i's per block

__device__ __forceinline__ unsigned short f2bf(float f) {
    unsigned int u = __float_as_uint(f);
    return (unsigned short)((u + 0x7fffu + ((u >> 16) & 1u)) >> 16);
}

template<int CTRL>
__device__ __forceinline__ float dppf(float x) {
    return __int_as_float(
        __builtin_amdgcn_update_dpp(0, __float_as_int(x), CTRL, 0xF, 0xF, true));
}
__device__ __forceinline__ float sum16(float x) {
    x += dppf<0x121>(x); x += dppf<0x122>(x);
    x += dppf<0x124>(x); x += dppf<0x128>(x);
    return x;
}
__device__ __forceinline__ float max16(float x) {
    x = fmaxf(x, dppf<0x121>(x)); x = fmaxf(x, dppf<0x122>(x));
    x = fmaxf(x, dppf<0x124>(x)); x = fmaxf(x, dppf<0x128>(x));
    return x;
}

// async global->LDS, 16B per lane; lds base wave-uniform, global src per-lane
__device__ __forceinline__ void gl2lds16(const void* gsrc, void* ldst) {
    __builtin_amdgcn_global_load_lds(
        (const __attribute__((address_space(1))) void*)gsrc,
        (__attribute__((address_space(3))) void*)ldst, 16, 0, 0);
}

__device__ __forceinline__ void barrier_lgkm() {
    asm volatile("s_waitcnt lgkmcnt(0)" ::: "memory");
    __builtin_amdgcn_s_barrier();
    __builtin_amdgcn_sched_barrier(0);
}

// ---------------- conversion kernels ----------------

// Wt[i][h][n][8] <- W[j][i][p][q] fp32  (n = j*32+p)
__global__ __launch_bounds__(256)
void conv_w(const float* __restrict__ W, unsigned short* __restrict__ Wt) {
    const int t = blockIdx.x * 256 + threadIdx.x;          // (i,n)
    const int i = t >> 10, n = t & 1023;
    const float* src = W + ((((n >> 5) * I_DIM + i) * 32 + (n & 31)) << 4);
    unsigned int o[8];
    #pragma unroll
    for (int k = 0; k < 8; ++k)
        o[k] = (unsigned int)f2bf(src[2 * k]) | ((unsigned int)f2bf(src[2 * k + 1]) << 16);
    uint4* d0 = reinterpret_cast<uint4*>(Wt + (((size_t)i * 2 + 0) * 1024 + n) * 8);
    uint4* d1 = reinterpret_cast<uint4*>(Wt + (((size_t)i * 2 + 1) * 1024 + n) * 8);
    *d0 = make_uint4(o[0], o[1], o[2], o[3]);
    *d1 = make_uint4(o[4], o[5], o[6], o[7]);
}

// xT2[i][g][b][8] <- x[b][i][q] fp32  (g0/1 = hi q0-7/q8-15, g2/3 = lo residual)
__global__ __launch_bounds__(256)
void conv_x(const float* __restrict__ x, unsigned short* __restrict__ xT2) {
    const int t = blockIdx.x * 256 + threadIdx.x;          // (i,b)
    const int i = t >> 6, b = t & 63;
    const float* src = x + (((size_t)b * I_DIM + i) << 4);
    unsigned int o[16];
    #pragma unroll
    for (int k = 0; k < 8; ++k) {
        const float f0 = src[2 * k], f1 = src[2 * k + 1];
        const unsigned short h0 = f2bf(f0), h1 = f2bf(f1);
        const float l0 = f0 - __uint_as_float(((unsigned int)h0) << 16);
        const float l1 = f1 - __uint_as_float(((unsigned int)h1) << 16);
        o[k]     = (unsigned int)h0       | ((unsigned int)h1 << 16);
        o[8 + k] = (unsigned int)f2bf(l0) | ((unsigned int)f2bf(l1) << 16);
    }
    #pragma unroll
    for (int g = 0; g < 4; ++g) {
        uint4* dst = reinterpret_cast<uint4*>(xT2 + (((size_t)i * 4 + g) * 64 + b) * 8);
        *dst = make_uint4(o[4 * g], o[4 * g + 1], o[4 * g + 2], o[4 * g + 3]);
    }
}

// ---------------- fused routing pass ----------------
// Block: 512 thr = 8 waves; one 16-b group x all 1024 n; TI=16 i's.
// Wave w: j in [4w, 4w+4) -> 8 N-tiles (t = jj*2+ph). Wt tile (32KB) + x tile
// (1KB) double-buffered in LDS; stage(i+2) issued mid-iter, awaited next iter
// with counted vmcnt (wave 0-6: 4 instrs, wave 7: +x = 5).
#define WAITC() do { if (w == 7) asm volatile("s_waitcnt vmcnt(5)" ::: "memory"); \
                     else        asm volatile("s_waitcnt vmcnt(4)" ::: "memory"); } while (0)

template<int ROUTED>
__global__ __launch_bounds__(512, 2)
void caps_fused(const unsigned short* __restrict__ Wt,   // [I][2][1024][8]
                const unsigned short* __restrict__ xT2,  // [I][4][64][8]
                const float* __restrict__ v_in,          // [64][32][32] (ROUTED)
                float* __restrict__ s_out)               // [64][1024]
{
    __shared__ short wbuf[2][16384];   // [h][n][8] per buf (32 KB)
    __shared__ short xbuf[2][512];     // [g][b-local][8] per buf (1 KB)
    __shared__ float d_buf[16 * 36];
    __shared__ float c_buf[16 * 36];

    const int tid = threadIdx.x;
    const int w   = tid >> 6;
    const int l   = tid & 63;
    const int g   = l >> 4;
    const int li  = l & 15;
    const int j0  = w << 2;            // 4 j per wave

    // XCD-chunked bijective swizzle (512 blocks)
    const int bid = (int)blockIdx.x;
    const int V   = (bid & 7) * 64 + (bid >> 3);
    const int it  = V >> 2;
    const int b0  = (V & 3) << 4;
    const int i0  = it * TI;

    // v in registers (ROUTED): vr[r][t] = v[b0+4g+r][j0+(t>>1)][(t&1)*16+li]
    float vr[4][8];
    if (ROUTED) {
        #pragma unroll
        for (int r = 0; r < 4; ++r)
            #pragma unroll
            for (int t = 0; t < 8; ++t)
                vr[r][t] = v_in[((b0 + (g << 2) + r) * 32 + j0 + (t >> 1)) * 32
                                + ((t & 1) << 4) + li];
        asm volatile("s_waitcnt vmcnt(0)" ::: "memory");   // clean count for stages
    }

    // stage i into buffer bufn: wave w stages Wt chunks 4w..4w+3 (1KB each);
    // wave 7 also stages the x tile (per-lane src = pre-swizzled gather).
    auto stage = [&](int i, int bufn) {
        const unsigned short* wsrc = Wt + ((size_t)i << 14);
        #pragma unroll
        for (int k = 0; k < 4; ++k) {
            const int c = (w << 2) + k;
            gl2lds16(wsrc + (c << 9) + (l << 3), &wbuf[bufn][c << 9]);
        }
        if (w == 7)
            gl2lds16(xT2 + (((size_t)i << 2) + (l >> 4)) * 512 + ((b0 + (l & 15)) << 3),
                     &xbuf[bufn][0]);
    };

    stage(i0, 0);
    stage(i0 + 1, 1);
    WAITC();                            // stage(i0) complete
    __builtin_amdgcn_s_barrier();
    __builtin_amdgcn_sched_barrier(0);

    ffrag s[8];
    #pragma unroll
    for (int t = 0; t < 8; ++t) s[t] = ffrag{0.f, 0.f, 0.f, 0.f};

    for (int ii = 0; ii < TI; ++ii) {
        const int cur = ii & 1;

        const bfrag a = *reinterpret_cast<const bfrag*>(&xbuf[cur][((g << 4) + li) << 3]);
        ffrag u[8];
        #pragma unroll
        for (int t = 0; t < 8; ++t) {
            const int n0 = ((j0 + (t >> 1)) << 5) + ((t & 1) << 4);
            const bfrag bt = *reinterpret_cast<const bfrag*>(
                &wbuf[cur][((g & 1) << 13) + ((n0 + li) << 3)]);
            if (ROUTED) {
                ffrag z{0.f, 0.f, 0.f, 0.f};
                u[t] = __builtin_amdgcn_mfma_f32_16x16x32_bf16(a, bt, z, 0, 0, 0);
            } else {
                s[t] = __builtin_amdgcn_mfma_f32_16x16x32_bf16(a, bt, s[t], 0, 0, 0);
            }
        }

        if (ROUTED) {
            // d[b,j] = sum_p v*u (p = (t&1)*16+li), DPP 16-lane reduce
            #pragma unroll
            for (int r = 0; r < 4; ++r) {
                float d0 = u[0][r] * vr[r][0] + u[1][r] * vr[r][1];
                float d1 = u[2][r] * vr[r][2] + u[3][r] * vr[r][3];
                float d2 = u[4][r] * vr[r][4] + u[5][r] * vr[r][5];
                float d3 = u[6][r] * vr[r][6] + u[7][r] * vr[r][7];
                d0 = sum16(d0); d1 = sum16(d1); d2 = sum16(d2); d3 = sum16(d3);
                float sel = d0;
                sel = (li == 1) ? d1 : sel;
                sel = (li == 2) ? d2 : sel;
                sel = (li == 3) ? d3 : sel;
                if (li < 4) d_buf[((g << 2) + r) * 36 + j0 + li] = sel;
            }
        }
        barrier_lgkm();   // B1: d_buf ready AND all reads of buf[cur] complete

        if (ii + 2 < TI) stage(i0 + ii + 2, cur);   // overwrite-safe after B1

        if (ROUTED) {
            // softmax over j: 2 rows per wave (row = (i-local) b-row)
            const int row = (w << 1) + (l >> 5), jx = l & 31;
            const float dv = d_buf[row * 36 + jx];
            float m = max16(dv);
            m = fmaxf(m, __shfl_xor(m, 16));
            const float e = __expf(dv - m);
            float sm = sum16(e);
            sm += __shfl_xor(sm, 16);
            c_buf[row * 36 + jx] = e / sm;
            barrier_lgkm();   // B2: c_buf ready

            #pragma unroll
            for (int r = 0; r < 4; ++r) {
                const ffrag cr = *reinterpret_cast<const ffrag*>(
                    &c_buf[((g << 2) + r) * 36 + j0]);   // 16B-aligned broadcast
                #pragma unroll
                for (int t = 0; t < 8; ++t)
                    s[t][r] += cr[t >> 1] * u[t][r];
            }
        }

        // B3: stage(i+1) (next buffer) must be complete before next iter reads
        if (ii + 2 < TI) WAITC();
        else             asm volatile("s_waitcnt vmcnt(0)" ::: "memory");
        __builtin_amdgcn_s_barrier();
        __builtin_amdgcn_sched_barrier(0);
    }

    const float sc = ROUTED ? 1.f : (1.f / 32.f);
    #pragma unroll
    for (int t = 0; t < 8; ++t) {
        const int n0 = ((j0 + (t >> 1)) << 5) + ((t & 1) << 4);
        #pragma unroll
        for (int r = 0; r < 4; ++r)
            atomicAdd(&s_out[(size_t)(b0 + (g << 2) + r) * N_DIM + n0 + li],
                      s[t][r] * sc);
    }
}

// dst[row] = (base ? base[row] : 0) + squash(s[row]),  row = (b,j)
__global__ __launch_bounds__(256)
void squash_add(const float* __restrict__ s, const float* __restrict__ base,
                float* __restrict__ dst) {
    const int t = blockIdx.x * 256 + threadIdx.x;
    if (t >= B_DIM * 32) return;
    const float* sp = s + t * 32;
    float n2 = 0.f;
    #pragma unroll
    for (int p = 0; p < 32; ++p) { const float xv = sp[p]; n2 += xv * xv; }
    const float scl = n2 / ((1.f + n2) * sqrtf(n2 + 1e-7f));
    float* op = dst + t * 32;
    #pragma unroll
    for (int p = 0; p < 32; ++p)
        op[p] = (base ? base[t * 32 + p] : 0.f) + scl * sp[p];
}

} // namespace

extern "C" void kernel_launch(void* const* d_in, const int* in_sizes, int n_in,
                              void* d_out, int out_size, void* d_ws, size_t ws_size,
                              hipStream_t stream) {
    const float* x = (const float*)d_in[0];   // [64, 2048, 16]
    const float* W = (const float*)d_in[1];   // [32, 2048, 32, 16]
    float* out = (float*)d_out;               // [64, 32, 32]

    const size_t needW = (size_t)I_DIM * 2 * 1024 * 8 * 2;   // 64 MB bf16 Wt
    const size_t needX = (size_t)I_DIM * 4 * 64 * 8 * 2;     // 8 MB bf16 xT2
    const size_t needS = (size_t)B_DIM * N_DIM * 4;          // 256 KB

    char* pp = (char*)d_ws;
    unsigned short* Wt  = (unsigned short*)pp; pp += needW;
    unsigned short* xT2 = (unsigned short*)pp; pp += needX;
    float* s  = (float*)pp; pp += needS;
    float* v1 = (float*)pp; pp += needS;
    float* vs = (float*)pp;
    (void)ws_size;

    conv_x<<<(I_DIM * B_DIM) / 256, 256, 0, stream>>>(x, xT2);
    conv_w<<<(I_DIM * N_DIM) / 256, 256, 0, stream>>>(W, Wt);

    const dim3 rg(512), rb(512);

    // pass A: uniform c = 1/32
    hipMemsetAsync(s, 0, needS, stream);
    caps_fused<0><<<rg, rb, 0, stream>>>(Wt, xT2, nullptr, s);
    squash_add<<<8, 256, 0, stream>>>(s, nullptr, v1);

    // pass B: v = v1
    hipMemsetAsync(s, 0, needS, stream);
    caps_fused<1><<<rg, rb, 0, stream>>>(Wt, xT2, v1, s);
    squash_add<<<8, 256, 0, stream>>>(s, v1, vs);           // vs = v1 + v2

    // pass C: v = v1+v2 (logits linear in v)
    hipMemsetAsync(s, 0, needS, stream);
    caps_fused<1><<<rg, rb, 0, stream>>>(Wt, xT2, vs, s);
    squash_add<<<8, 256, 0, stream>>>(s, nullptr, out);
}

// Round 7
// 265.295 us; speedup vs baseline: 1.3351x; 1.0799x over previous
//
#include <hip/hip_runtime.h>

// DigitCaps dynamic routing, MI355X — round 7: occupancy-driven redesign.
// r6 diagnosis: combined VGPR+AGPR ~136 > 128 -> 1 block/CU -> 2 waves/SIMD
// -> 73% idle. r7: 16-wave block (4 waves/SIMD, regs <= 128), ONE barrier per
// iteration (softmax(i-1) || MFMA u(i) || stage(i+3), counted vmcnt, u-dbuf
// pipeline), quad-buffered LDS staging (132 KB, 1 block/CU by design).
//
// u_hat[b,j,i,p] = sum_q x[b,i,q] W[j,i,p,q];  b=64, i=2048, j=32, p=32, q=16
// Pass A: s1 = (1/32) sum_i u_hat ; v1 = squash(s1)
// Pass B: per i: d=sum_p v1*u_hat ; c=softmax_j d ; s2 += c*u_hat ; v2=squash
// Pass C: v = v1+v2 (logits linear in v) ; out = squash(s3)
//
// MFMA 16x16x32 bf16: A k0-15 = hi(x), k16-31 = lo residual; B k-halves
// replicate W => A-side fp32-exact, only W rounded once (absmax ~4e-3).
// Layouts: Wt[i][h][n][8] bf16 (h = q-half), xT2[i][g][b][8] bf16 (g = k-grp).

namespace {

using bfrag = __attribute__((ext_vector_type(8))) short;   // 8 bf16 = 4 VGPR
using ffrag = __attribute__((ext_vector_type(4))) float;   // 4 fp32 acc

constexpr int I_DIM = 2048;
constexpr int B_DIM = 64;
constexpr int N_DIM = 1024;
constexpr int TI    = 16;     // i's per block

__device__ __forceinline__ unsigned short f2bf(float f) {
    unsigned int u = __float_as_uint(f);
    return (unsigned short)((u + 0x7fffu + ((u >> 16) & 1u)) >> 16);
}

template<int CTRL>
__device__ __forceinline__ float dppf(float x) {
    return __int_as_float(
        __builtin_amdgcn_update_dpp(0, __float_as_int(x), CTRL, 0xF, 0xF, true));
}
__device__ __forceinline__ float sum16(float x) {
    x += dppf<0x121>(x); x += dppf<0x122>(x);
    x += dppf<0x124>(x); x += dppf<0x128>(x);
    return x;
}
__device__ __forceinline__ float max16(float x) {
    x = fmaxf(x, dppf<0x121>(x)); x = fmaxf(x, dppf<0x122>(x));
    x = fmaxf(x, dppf<0x124>(x)); x = fmaxf(x, dppf<0x128>(x));
    return x;
}

__device__ __forceinline__ void gl2lds16(const void* gsrc, void* ldst) {
    __builtin_amdgcn_global_load_lds(
        (const __attribute__((address_space(1))) void*)gsrc,
        (__attribute__((address_space(3))) void*)ldst, 16, 0, 0);
}

__device__ __forceinline__ void barrier_lgkm() {
    asm volatile("s_waitcnt lgkmcnt(0)" ::: "memory");
    __builtin_amdgcn_s_barrier();
    __builtin_amdgcn_sched_barrier(0);
}

// wait until own-wave stage(i+1) landed: outstanding <= 2 stages' worth.
// waves 0-14 issue 2 global_load_lds per stage, wave 15 issues 3.
#define WAITC() do {                                                          \
    if (w == 15) asm volatile("s_waitcnt vmcnt(6)" ::: "memory");             \
    else         asm volatile("s_waitcnt vmcnt(4)" ::: "memory");             \
} while (0)

// ---------------- conversion kernels ----------------

// Wt[i][h][n][8] <- W[j][i][p][q] fp32  (n = j*32+p, h = q-half)
__global__ __launch_bounds__(256)
void conv_w(const float* __restrict__ W, unsigned short* __restrict__ Wt) {
    const int t = blockIdx.x * 256 + threadIdx.x;          // (i,n)
    const int i = t >> 10, n = t & 1023;
    const float* src = W + ((((n >> 5) * I_DIM + i) * 32 + (n & 31)) << 4);
    unsigned int o[8];
    #pragma unroll
    for (int k = 0; k < 8; ++k)
        o[k] = (unsigned int)f2bf(src[2 * k]) | ((unsigned int)f2bf(src[2 * k + 1]) << 16);
    uint4* d0 = reinterpret_cast<uint4*>(Wt + (((size_t)i * 2 + 0) * 1024 + n) * 8);
    uint4* d1 = reinterpret_cast<uint4*>(Wt + (((size_t)i * 2 + 1) * 1024 + n) * 8);
    *d0 = make_uint4(o[0], o[1], o[2], o[3]);
    *d1 = make_uint4(o[4], o[5], o[6], o[7]);
}

// xT2[i][g][b][8] <- x[b][i][q] fp32  (g0/1 = hi q0-7/q8-15, g2/3 = lo residual)
__global__ __launch_bounds__(256)
void conv_x(const float* __restrict__ x, unsigned short* __restrict__ xT2) {
    const int t = blockIdx.x * 256 + threadIdx.x;          // (i,b)
    const int i = t >> 6, b = t & 63;
    const float* src = x + (((size_t)b * I_DIM + i) << 4);
    unsigned int o[16];
    #pragma unroll
    for (int k = 0; k < 8; ++k) {
        const float f0 = src[2 * k], f1 = src[2 * k + 1];
        const unsigned short h0 = f2bf(f0), h1 = f2bf(f1);
        const float l0 = f0 - __uint_as_float(((unsigned int)h0) << 16);
        const float l1 = f1 - __uint_as_float(((unsigned int)h1) << 16);
        o[k]     = (unsigned int)h0       | ((unsigned int)h1 << 16);
        o[8 + k] = (unsigned int)f2bf(l0) | ((unsigned int)f2bf(l1) << 16);
    }
    #pragma unroll
    for (int g = 0; g < 4; ++g) {
        uint4* dst = reinterpret_cast<uint4*>(xT2 + (((size_t)i * 4 + g) * 64 + b) * 8);
        *dst = make_uint4(o[4 * g], o[4 * g + 1], o[4 * g + 2], o[4 * g + 3]);
    }
}

// ---------------- fused routing pass ----------------
// Block: 1024 thr = 16 waves; one 16-b group x all 1024 n; TI=16 i's.
// Wave w: j = {2w, 2w+1} -> 4 N-tiles (t: jj = t>>1, p-half = t&1).
// Per iter: softmax(i-1) || MFMA u(i) || d-part(i) || stage(i+3); WAITC;
// ONE lgkm-barrier; apply(i-1) with u from the 2-deep register pipeline.
template<int ROUTED>
__global__ __launch_bounds__(1024, 4)
void caps_fused(const unsigned short* __restrict__ Wt,   // [I][2][1024][8]
                const unsigned short* __restrict__ xT2,  // [I][4][64][8]
                const float* __restrict__ v_in,          // [64][32][32] (ROUTED)
                float* __restrict__ s_out)               // [64][1024]
{
    __shared__ __align__(16) short wbuf[4][16384];   // 128 KB quad-buffer
    __shared__ __align__(16) short xbuf[4][512];     //   4 KB quad-buffer
    __shared__ __align__(16) float d_buf[2][16 * 36];
    __shared__ __align__(16) float c_buf[2][16 * 36];

    const int tid = threadIdx.x;
    const int w   = tid >> 6;          // wave 0..15
    const int l   = tid & 63;
    const int g   = l >> 4;            // 16-lane group 0..3
    const int li  = l & 15;
    const int j0  = w << 1;            // 2 j per wave

    // XCD-chunked bijective swizzle: 4 same-i_tile b-group blocks -> same XCD
    const int bid = (int)blockIdx.x;
    const int V   = (bid & 7) * 64 + (bid >> 3);
    const int it  = V >> 2;
    const int b0  = (V & 3) << 4;
    const int i0  = it * TI;

    float vr[4][4];
    if (ROUTED) {
        #pragma unroll
        for (int r = 0; r < 4; ++r)
            #pragma unroll
            for (int t = 0; t < 4; ++t)
                vr[r][t] = v_in[((b0 + (g << 2) + r) * 32 + j0 + (t >> 1)) * 32
                                + ((t & 1) << 4) + li];
        asm volatile("s_waitcnt vmcnt(0)" ::: "memory");   // clean vm count
    }

    // stage i into rotation slot bn: waves 0-15 each move 2 KB of Wt (2 instr);
    // wave 15 also stages the x tile (per-lane gathered source, linear dest).
    auto stage = [&](int i, int bn) {
        const unsigned short* wsrc = Wt + ((size_t)i << 14);
        #pragma unroll
        for (int k = 0; k < 2; ++k) {
            const int rr0 = (k << 10) + (w << 6);          // row of 8 shorts
            gl2lds16(wsrc + ((size_t)(rr0 + l) << 3), &wbuf[bn][rr0 << 3]);
        }
        if (w == 15)
            gl2lds16(xT2 + (((size_t)i << 2) + (l >> 4)) * 512
                         + ((size_t)(b0 + (l & 15)) << 3),
                     &xbuf[bn][0]);
    };

    stage(i0, 0); stage(i0 + 1, 1); stage(i0 + 2, 2);
    WAITC();                            // stage(i0) landed (own wave)
    barrier_lgkm();                     // cross-wave: buf0 fully ready

    ffrag s[4];
    #pragma unroll
    for (int t = 0; t < 4; ++t) s[t] = ffrag{0.f, 0.f, 0.f, 0.f};

    if constexpr (!ROUTED) {
        for (int ii = 0; ii < TI; ++ii) {
            const int cur4 = ii & 3;
            const bfrag a = *reinterpret_cast<const bfrag*>(
                &xbuf[cur4][((g << 4) + li) << 3]);
            #pragma unroll
            for (int t = 0; t < 4; ++t) {
                const int n0 = ((j0 + (t >> 1)) << 5) + ((t & 1) << 4);
                const bfrag bt = *reinterpret_cast<const bfrag*>(
                    &wbuf[cur4][((g & 1) << 13) + ((n0 + li) << 3)]);
                s[t] = __builtin_amdgcn_mfma_f32_16x16x32_bf16(a, bt, s[t], 0, 0, 0);
            }
            stage(i0 + ((ii + 3 < TI) ? ii + 3 : TI - 1), (ii + 3) & 3);
            WAITC();
            barrier_lgkm();
        }
    } else {
        ffrag uA[4], uB[4];
        #pragma unroll
        for (int t = 0; t < 4; ++t) uA[t] = ffrag{0.f, 0.f, 0.f, 0.f};

        auto one_iter = [&](int ii, ffrag (&up)[4], ffrag (&un)[4]) {
            const int cur2 = ii & 1, p2 = cur2 ^ 1, cur4 = ii & 3;

            // A: softmax(i-1) — 1 row per wave, lanes 0..31 (reads d_buf[p2])
            if (ii > 0 && l < 32) {
                const float dv = d_buf[p2][w * 36 + l];
                float m = max16(dv);
                m = fmaxf(m, __shfl_xor(m, 16));
                const float e = __expf(dv - m);
                float sm = sum16(e);
                sm += __shfl_xor(sm, 16);
                c_buf[p2][w * 36 + l] = e / sm;
            }

            // B: MFMA u(ii) from staged buffers
            const bfrag a = *reinterpret_cast<const bfrag*>(
                &xbuf[cur4][((g << 4) + li) << 3]);
            const ffrag z{0.f, 0.f, 0.f, 0.f};
            #pragma unroll
            for (int t = 0; t < 4; ++t) {
                const int n0 = ((j0 + (t >> 1)) << 5) + ((t & 1) << 4);
                const bfrag bt = *reinterpret_cast<const bfrag*>(
                    &wbuf[cur4][((g & 1) << 13) + ((n0 + li) << 3)]);
                un[t] = __builtin_amdgcn_mfma_f32_16x16x32_bf16(a, bt, z, 0, 0, 0);
            }

            // C: d-partials(ii) -> d_buf[cur2] (DPP 16-lane p-reduce)
            #pragma unroll
            for (int r = 0; r < 4; ++r) {
                float d0 = un[0][r] * vr[r][0] + un[1][r] * vr[r][1];
                float d1 = un[2][r] * vr[r][2] + un[3][r] * vr[r][3];
                d0 = sum16(d0);
                d1 = sum16(d1);
                const float dsel = (li & 1) ? d1 : d0;
                if (li < 2) d_buf[cur2][((g << 2) + r) * 36 + j0 + li] = dsel;
            }

            // F: stage(ii+3) into its rotation slot (prev readers done @ E(ii-1))
            stage(i0 + ((ii + 3 < TI) ? ii + 3 : TI - 1), (ii + 3) & 3);

            // WAITC before the barrier: own stage(i+1) landed -> after the
            // barrier ALL waves' stage(i+1) is visible (safe cross-wave idiom).
            WAITC();
            barrier_lgkm();   // E: publishes d_buf[cur2], c_buf[p2]

            // G: apply(i-1): s += c(i-1) * u(i-1)
            if (ii > 0) {
                #pragma unroll
                for (int r = 0; r < 4; ++r) {
                    const float2 cr = *reinterpret_cast<const float2*>(
                        &c_buf[p2][((g << 2) + r) * 36 + j0]);
                    s[0][r] += cr.x * up[0][r];
                    s[1][r] += cr.x * up[1][r];
                    s[2][r] += cr.y * up[2][r];
                    s[3][r] += cr.y * up[3][r];
                }
            }
        };

        for (int cc = 0; cc < TI / 2; ++cc) {
            one_iter(2 * cc,     uA, uB);
            one_iter(2 * cc + 1, uB, uA);
        }

        // epilogue: softmax(i15) + apply(i15); u(i15) lives in uA
        if (l < 32) {
            const float dv = d_buf[1][w * 36 + l];
            float m = max16(dv);
            m = fmaxf(m, __shfl_xor(m, 16));
            const float e = __expf(dv - m);
            float sm = sum16(e);
            sm += __shfl_xor(sm, 16);
            c_buf[1][w * 36 + l] = e / sm;
        }
        barrier_lgkm();
        #pragma unroll
        for (int r = 0; r < 4; ++r) {
            const float2 cr = *reinterpret_cast<const float2*>(
                &c_buf[1][((g << 2) + r) * 36 + j0]);
            s[0][r] += cr.x * uA[0][r];
            s[1][r] += cr.x * uA[1][r];
            s[2][r] += cr.y * uA[2][r];
            s[3][r] += cr.y * uA[3][r];
        }
    }

    asm volatile("s_waitcnt vmcnt(0)" ::: "memory");   // drain tail stages
    const float sc = ROUTED ? 1.f : (1.f / 32.f);
    #pragma unroll
    for (int t = 0; t < 4; ++t)
        #pragma unroll
        for (int r = 0; r < 4; ++r)
            atomicAdd(&s_out[(size_t)(b0 + (g << 2) + r) * N_DIM
                             + ((j0 + (t >> 1)) << 5) + ((t & 1) << 4) + li],
                      s[t][r] * sc);
}

// dst[row] = (base ? base[row] : 0) + squash(s[row]),  row = (b,j)
__global__ __launch_bounds__(256)
void squash_add(const float* __restrict__ s, const float* __restrict__ base,
                float* __restrict__ dst) {
    const int t = blockIdx.x * 256 + threadIdx.x;
    if (t >= B_DIM * 32) return;
    const float* sp = s + t * 32;
    float n2 = 0.f;
    #pragma unroll
    for (int p = 0; p < 32; ++p) { const float xv = sp[p]; n2 += xv * xv; }
    const float scl = n2 / ((1.f + n2) * sqrtf(n2 + 1e-7f));
    float* op = dst + t * 32;
    #pragma unroll
    for (int p = 0; p < 32; ++p)
        op[p] = (base ? base[t * 32 + p] : 0.f) + scl * sp[p];
}

} // namespace

extern "C" void kernel_launch(void* const* d_in, const int* in_sizes, int n_in,
                              void* d_out, int out_size, void* d_ws, size_t ws_size,
                              hipStream_t stream) {
    const float* x = (const float*)d_in[0];   // [64, 2048, 16]
    const float* W = (const float*)d_in[1];   // [32, 2048, 32, 16]
    float* out = (float*)d_out;               // [64, 32, 32]

    const size_t needW = (size_t)I_DIM * 2 * 1024 * 8 * 2;   // 64 MB bf16 Wt
    const size_t needX = (size_t)I_DIM * 4 * 64 * 8 * 2;     // 8 MB bf16 xT2
    const size_t needS = (size_t)B_DIM * N_DIM * 4;          // 256 KB

    char* pp = (char*)d_ws;
    unsigned short* Wt  = (unsigned short*)pp; pp += needW;
    unsigned short* xT2 = (unsigned short*)pp; pp += needX;
    float* s  = (float*)pp; pp += needS;
    float* v1 = (float*)pp; pp += needS;
    float* vs = (float*)pp;
    (void)ws_size;

    conv_x<<<(I_DIM * B_DIM) / 256, 256, 0, stream>>>(x, xT2);
    conv_w<<<(I_DIM * N_DIM) / 256, 256, 0, stream>>>(W, Wt);

    const dim3 rg(512), rb(1024);

    // pass A: uniform c = 1/32
    hipMemsetAsync(s, 0, needS, stream);
    caps_fused<0><<<rg, rb, 0, stream>>>(Wt, xT2, nullptr, s);
    squash_add<<<8, 256, 0, stream>>>(s, nullptr, v1);

    // pass B: v = v1
    hipMemsetAsync(s, 0, needS, stream);
    caps_fused<1><<<rg, rb, 0, stream>>>(Wt, xT2, v1, s);
    squash_add<<<8, 256, 0, stream>>>(s, v1, vs);           // vs = v1 + v2

    // pass C: v = v1+v2 (logits linear in v)
    hipMemsetAsync(s, 0, needS, stream);
    caps_fused<1><<<rg, rb, 0, stream>>>(Wt, xT2, vs, s);
    squash_add<<<8, 256, 0, stream>>>(s, nullptr, out);
}